// Round 13
// baseline (577.821 us; speedup 1.0000x reference)
//
#include <hip/hip_runtime.h>
#include <hip/hip_bf16.h>

#define FD 128   // IN == HID == 128
#define OD 64    // OUT

typedef __hip_bfloat16 bf16;
typedef unsigned int u32;
typedef unsigned short u16;
typedef __attribute__((ext_vector_type(8))) short short8;   // 8 bf16 (4 VGPRs) MFMA A/B frag
typedef __attribute__((ext_vector_type(4))) float f32x4;    // 4 f32 MFMA C/D frag

__device__ __forceinline__ float b2f(bf16 x) { return __bfloat162float(x); }
__device__ __forceinline__ float ldf(const float* p, size_t i) { return p[i]; }
__device__ __forceinline__ float ldf(const bf16* p, size_t i) { return __bfloat162float(p[i]); }
__device__ __forceinline__ float us2f(u16 u) {
    union { float f; u32 i; } w; w.i = ((u32)u) << 16; return w.f;
}
__device__ __forceinline__ u16 f2us(float f) {
    bf16 h = __float2bfloat16(f);
    return *reinterpret_cast<u16*>(&h);
}
// load 2 consecutive elements (bf16 world: single aligned 4B uint load)
template <typename T>
__device__ __forceinline__ void ld2(const T* p, size_t i, float& a, float& b) {
    if constexpr (sizeof(T) == 2) {
        u32 v = *(const u32*)((const u16*)p + i);   // i is even -> 4B aligned
        a = us2f((u16)(v & 0xffff));
        b = us2f((u16)(v >> 16));
    } else {
        a = p[i]; b = p[i + 1];
    }
}

// ---------- dtype sniffer: bf16 data -> sane exponents; fp32 read as u16 -> garbage ----------
__global__ void k_sniff(const u16* w1raw, unsigned* flag) {
    int t = threadIdx.x;                 // 64 threads
    int insane = 0;
    for (int i = t; i < 128; i += 64) {
        unsigned e = (w1raw[i] >> 7) & 0xFF;
        if (e != 0 && (e < 100 || e > 140)) insane++;
    }
    for (int o = 32; o > 0; o >>= 1) insane += __shfl_down(insane, o);
    if (t == 0) *flag = (insane > 16) ? 1u : 0u;   // 0 = bf16 world, 1 = fp32 world
}

// ---------- degree count ----------
__global__ void k_deg(const int* __restrict__ src, const int* __restrict__ dst,
                      unsigned* __restrict__ deg_s, unsigned* __restrict__ deg_d, int E) {
    int i = blockIdx.x * blockDim.x + threadIdx.x;
    if (i < E) {
        atomicAdd(&deg_s[src[i]], 1u);
        atomicAdd(&deg_d[dst[i]], 1u);
    }
}

// ---------- scan stage 1 FUSED with cnorm ----------
__global__ void k_scan1(const unsigned* __restrict__ deg_s, const unsigned* __restrict__ deg_d,
                        float* __restrict__ c_src, float* __restrict__ c_dst,
                        unsigned* __restrict__ bsum, int n) {
    __shared__ unsigned red[256];
    int t = threadIdx.x, i = blockIdx.x * 256 + t;
    unsigned v = 0u;
    if (i < n) {
        unsigned ds = deg_s[i];
        v = deg_d[i];
        c_src[i] = rsqrtf(fmaxf((float)ds, 1.0f));
        c_dst[i] = rsqrtf(fmaxf((float)v, 1.0f));
    }
    red[t] = v;
    __syncthreads();
    for (int o = 128; o > 0; o >>= 1) {
        if (t < o) red[t] += red[t + o];
        __syncthreads();
    }
    if (t == 0) bsum[blockIdx.x] = red[0];
}

// ---------- scan stage 2 ----------
__global__ void k_scan2(const unsigned* __restrict__ bsum, unsigned* __restrict__ bpre, int nb) {
    __shared__ unsigned s[512];
    int t = threadIdx.x;
    unsigned v = (t < nb) ? bsum[t] : 0u;
    s[t] = v;
    __syncthreads();
    for (int o = 1; o < 512; o <<= 1) {
        unsigned x = (t >= o) ? s[t - o] : 0u;
        __syncthreads();
        s[t] += x;
        __syncthreads();
    }
    if (t < nb) bpre[t] = s[t] - v;
}

// ---------- scan stage 3: row_ptr + cursor ----------
__global__ void k_scan3(const unsigned* __restrict__ deg, const unsigned* __restrict__ bpre,
                        unsigned* __restrict__ row_ptr, unsigned* __restrict__ cursor,
                        int n, int E) {
    __shared__ unsigned s[256];
    int t = threadIdx.x, i = blockIdx.x * 256 + t;
    unsigned v = (i < n) ? deg[i] : 0u;
    s[t] = v;
    __syncthreads();
    for (int o = 1; o < 256; o <<= 1) {
        unsigned x = (t >= o) ? s[t - o] : 0u;
        __syncthreads();
        s[t] += x;
        __syncthreads();
    }
    unsigned excl = bpre[blockIdx.x] + s[t] - v;
    if (i < n) { row_ptr[i] = excl; cursor[i] = excl; }
    if (blockIdx.x == 0 && t == 0) row_ptr[n] = (unsigned)E;
}

// ---------- CSR fill FUSED with wsum ----------
__global__ void k_fill(const int* __restrict__ src, const int* __restrict__ dst,
                       unsigned* __restrict__ cursor, unsigned* __restrict__ col,
                       const float* __restrict__ c_dst, float* __restrict__ wsum, int E) {
    int e = blockIdx.x * blockDim.x + threadIdx.x;
    if (e < E) {
        int s = src[e], d = dst[e];
        unsigned p = atomicAdd(&cursor[d], 1u);
        col[p] = (unsigned)s;
        unsafeAtomicAdd(&wsum[s], c_dst[d]);
    }
}

// ---------- layer1 fused: round-12 gather (verbatim) -> bf16 LDS tile -> MFMA GEMM ----------
// Block = 64 nodes, wave w owns nodes [base+16w, base+16w+16) (wave-private xsb rows).
// A frag: xsb[m0+(l&15)][32s + 8q + 0..7]  (A[m][k], k=quad*8+j)
// B frag: Wt[16t+(l&15)][32s + 8q + 0..7]  (Wt[n][k] = W1[k][n] -> B[k][n])
// C/D:    col=lane&15 (n), row=quad*4+reg (m)
// Wt staged in 2 halves of 64 features -> LDS total ~40 KB -> 3 blocks/CU.
template <typename T>
__global__ __launch_bounds__(256) void k_layer1(const unsigned* __restrict__ flag, unsigned want,
                                                const T* __restrict__ feat, const T* __restrict__ W1,
                                                const T* __restrict__ b1,
                                                const float* __restrict__ c_src,
                                                const float* __restrict__ c_dst,
                                                const float* __restrict__ wsum,
                                                const unsigned* __restrict__ row_ptr,
                                                const unsigned* __restrict__ col,
                                                float* __restrict__ accum128, int n) {
    if (*flag != want) return;
    __shared__ __align__(16) u16 Wt[64 * 144];    // 18.0 KB; row stride 144 el = 288 B (16B-mult)
    __shared__ __align__(16) u16 xsb[64 * 144];   // 18.0 KB
    __shared__ float b1l[FD];
    __shared__ float cdl[64], wcl[64];
    __shared__ float part[4][FD];
    int t = threadIdx.x;
    int base = blockIdx.x * 64;

    if (t < FD) b1l[t] = ldf(b1, t);
    if (t < 64) {
        int rr = base + t;
        cdl[t] = (rr < n) ? c_dst[rr] : 0.0f;
        wcl[t] = (rr < n) ? wsum[rr] * c_src[rr] : 0.0f;
    }
    {   // stage Wt half 0: Wt[nn][k] = W1[k][nn]; lane-consecutive k -> conflict-free LDS writes
        int k = t & 127;
        for (int nn = t >> 7; nn < 64; nn += 2)
            Wt[nn * 144 + k] = f2us(ldf(W1, (size_t)k * FD + nn));
    }
    __syncthreads();

    int w = t >> 6, l = t & 63;
    int m0 = w * 16;                 // wave's local node base
    int q = l >> 4, lm = l & 15;
    int j0 = l * 2;                  // gather: lane owns features 2l, 2l+1

    // ---- gather 16 nodes (round-12 proven inner loop), store bf16 pairs to xsb ----
    for (int g = 0; g < 16; g++) {
        int node = base + m0 + g;
        float acc0 = 0.0f, acc1 = 0.0f;
        if (node < n) {
            unsigned qq = row_ptr[node], qe = row_ptr[node + 1];
            for (; qq + 4 <= qe; qq += 4) {
                unsigned s0 = col[qq], s1 = col[qq + 1], s2 = col[qq + 2], s3 = col[qq + 3];
                float a0, b0, a1, b1v, a2, b2, a3, b3;
                ld2(feat, (size_t)s0 * FD + j0, a0, b0);
                ld2(feat, (size_t)s1 * FD + j0, a1, b1v);
                ld2(feat, (size_t)s2 * FD + j0, a2, b2);
                ld2(feat, (size_t)s3 * FD + j0, a3, b3);
                float c0 = c_src[s0], c1 = c_src[s1], c2 = c_src[s2], c3 = c_src[s3];
                acc0 += c0 * a0 + c1 * a1 + c2 * a2 + c3 * a3;
                acc1 += c0 * b0 + c1 * b1v + c2 * b2 + c3 * b3;
            }
            for (; qq < qe; qq++) {
                unsigned s = col[qq];
                float a, b;
                ld2(feat, (size_t)s * FD + j0, a, b);
                float c = c_src[s];
                acc0 += c * a;
                acc1 += c * b;
            }
        }
        u32 pk = ((u32)f2us(acc1) << 16) | (u32)f2us(acc0);
        *(u32*)&xsb[(m0 + g) * 144 + j0] = pk;    // wave-private row: no barrier
    }

    // ---- A fragments (reused across all 8 N-tiles) ----
    short8 af[4];
    #pragma unroll
    for (int s = 0; s < 4; s++)
        af[s] = *(const short8*)&xsb[(m0 + lm) * 144 + s * 32 + q * 8];

    float psum[8];
    for (int h = 0; h < 2; h++) {
        if (h == 1) {
            __syncthreads();     // all waves done reading Wt half 0
            int k = t & 127;
            for (int nn = t >> 7; nn < 64; nn += 2)
                Wt[nn * 144 + k] = f2us(ldf(W1, (size_t)k * FD + 64 + nn));
            __syncthreads();
        }
        #pragma unroll
        for (int tt = 0; tt < 4; tt++) {
            f32x4 c = {0.0f, 0.0f, 0.0f, 0.0f};
            #pragma unroll
            for (int s = 0; s < 4; s++) {
                short8 bfr = *(const short8*)&Wt[(tt * 16 + lm) * 144 + s * 32 + q * 8];
                c = __builtin_amdgcn_mfma_f32_16x16x32_bf16(af[s], bfr, c, 0, 0, 0);
            }
            int nglob = h * 64 + tt * 16 + lm;
            float bb = b1l[nglob];
            float ps = 0.0f;
            #pragma unroll
            for (int r = 0; r < 4; r++) {
                int loc = m0 + q * 4 + r;    // block-local node of this C row
                float hv = fmaxf(c[r] * cdl[loc] + bb, 0.0f);
                ps += wcl[loc] * hv;
            }
            psum[h * 4 + tt] = ps;
        }
    }

    // ---- reduce psums across quads (lanes l, l+16, l+32, l+48 share feature) ----
    #pragma unroll
    for (int i = 0; i < 8; i++) {
        float v = psum[i];
        v += __shfl_down(v, 32);
        v += __shfl_down(v, 16);
        if (l < 16) part[w][(i >> 2) * 64 + (i & 3) * 16 + lm] = v;
    }
    __syncthreads();
    if (t < FD) {
        float v = part[0][t] + part[1][t] + part[2][t] + part[3][t];
        unsafeAtomicAdd(&accum128[t], v);
    }
}

// ---------- final tiny GEMM: out = (accum128/N) @ W2 + b2 ----------
template <typename T, typename TO>
__global__ void k_final(const unsigned* __restrict__ flag, unsigned want,
                        const float* __restrict__ accum128,
                        const T* __restrict__ W2, const T* __restrict__ b2v,
                        TO* __restrict__ out, float invN) {
    if (*flag != want) return;
    int j = threadIdx.x;   // 64 threads
    float acc = 0.0f;
    for (int k = 0; k < FD; k++) acc += accum128[k] * ldf(W2, (size_t)k * OD + j);
    float v = acc * invN + ldf(b2v, j);
    if constexpr (sizeof(TO) == 2) out[j] = __float2bfloat16(v);
    else                           out[j] = (TO)v;
}

extern "C" void kernel_launch(void* const* d_in, const int* in_sizes, int n_in,
                              void* d_out, int out_size, void* d_ws, size_t ws_size,
                              hipStream_t stream) {
    const int* src = (const int*)d_in[1];
    const int* dst = (const int*)d_in[2];
    int N = in_sizes[0] / FD;
    int E = in_sizes[1];

    // workspace: zeroed region is one contiguous span [4096, 1048576 + N*4)
    char* ws = (char*)d_ws;
    unsigned* flag     = (unsigned*)(ws);
    float*    accum128 = (float*)   (ws + 4096);      // zeroed
    unsigned* deg_s    = (unsigned*)(ws + 65536);     // zeroed (N*4 <= 400KB)
    unsigned* deg_d    = (unsigned*)(ws + 524288);    // zeroed
    float*    wsum     = (float*)   (ws + 1048576);   // zeroed
    float*    c_src    = (float*)   (ws + 1572864);
    float*    c_dst    = (float*)   (ws + 2097152);
    unsigned* bsum     = (unsigned*)(ws + 2564096);
    unsigned* bpre     = (unsigned*)(ws + 2568192);
    unsigned* row_ptr  = (unsigned*)(ws + 2621440);
    unsigned* cursor   = (unsigned*)(ws + 3145728);
    unsigned* col      = (unsigned*)(ws + 3670016);
    // total footprint: 3670016 + E*4 = ~10.1 MB

    hipMemsetAsync(ws + 4096, 0, (size_t)(1048576 - 4096) + (size_t)N * 4, stream);

    int nb = (N + 255) / 256;   // 391 <= 512

    k_sniff<<<1, 64, 0, stream>>>((const u16*)d_in[3], flag);
    k_deg<<<(E + 255) / 256, 256, 0, stream>>>(src, dst, deg_s, deg_d, E);
    k_scan1<<<nb, 256, 0, stream>>>(deg_s, deg_d, c_src, c_dst, bsum, N);
    k_scan2<<<1, 512, 0, stream>>>(bsum, bpre, nb);
    k_scan3<<<nb, 256, 0, stream>>>(deg_d, bpre, row_ptr, cursor, N, E);
    k_fill<<<(E + 255) / 256, 256, 0, stream>>>(src, dst, cursor, col, c_dst, wsum, E);

    int gl1 = (N + 63) / 64;
    k_layer1<bf16><<<gl1, 256, 0, stream>>>(flag, 0u, (const bf16*)d_in[0], (const bf16*)d_in[3],
                                            (const bf16*)d_in[4], c_src, c_dst, wsum,
                                            row_ptr, col, accum128, N);
    k_layer1<float><<<gl1, 256, 0, stream>>>(flag, 1u, (const float*)d_in[0], (const float*)d_in[3],
                                             (const float*)d_in[4], c_src, c_dst, wsum,
                                             row_ptr, col, accum128, N);

    float invN = 1.0f / (float)N;
    k_final<bf16, bf16><<<1, 64, 0, stream>>>(flag, 0u, accum128, (const bf16*)d_in[5],
                                              (const bf16*)d_in[6], (bf16*)d_out, invN);
    k_final<float, float><<<1, 64, 0, stream>>>(flag, 1u, accum128, (const float*)d_in[5],
                                                (const float*)d_in[6], (float*)d_out, invN);
}

// Round 14
// 562.316 us; speedup vs baseline: 1.0276x; 1.0276x over previous
//
#include <hip/hip_runtime.h>
#include <hip/hip_bf16.h>

#define FD 128   // IN == HID == 128
#define OD 64    // OUT

typedef __hip_bfloat16 bf16;
typedef unsigned int u32;
typedef unsigned short u16;
typedef __attribute__((ext_vector_type(8))) short short8;   // 8 bf16 (4 VGPRs) MFMA A/B frag
typedef __attribute__((ext_vector_type(4))) float f32x4;    // 4 f32 MFMA C/D frag

__device__ __forceinline__ float b2f(bf16 x) { return __bfloat162float(x); }
__device__ __forceinline__ float ldf(const float* p, size_t i) { return p[i]; }
__device__ __forceinline__ float ldf(const bf16* p, size_t i) { return __bfloat162float(p[i]); }
__device__ __forceinline__ float us2f(u16 u) {
    union { float f; u32 i; } w; w.i = ((u32)u) << 16; return w.f;
}
__device__ __forceinline__ u16 f2us(float f) {
    bf16 h = __float2bfloat16(f);
    return *reinterpret_cast<u16*>(&h);
}
// load 2 consecutive elements (bf16 world: single aligned 4B uint load)
template <typename T>
__device__ __forceinline__ void ld2(const T* p, size_t i, float& a, float& b) {
    if constexpr (sizeof(T) == 2) {
        u32 v = *(const u32*)((const u16*)p + i);   // i is even -> 4B aligned
        a = us2f((u16)(v & 0xffff));
        b = us2f((u16)(v >> 16));
    } else {
        a = p[i]; b = p[i + 1];
    }
}

// ---------- dtype sniffer: bf16 data -> sane exponents; fp32 read as u16 -> garbage ----------
__global__ void k_sniff(const u16* w1raw, unsigned* flag) {
    int t = threadIdx.x;                 // 64 threads
    int insane = 0;
    for (int i = t; i < 128; i += 64) {
        unsigned e = (w1raw[i] >> 7) & 0xFF;
        if (e != 0 && (e < 100 || e > 140)) insane++;
    }
    for (int o = 32; o > 0; o >>= 1) insane += __shfl_down(insane, o);
    if (t == 0) *flag = (insane > 16) ? 1u : 0u;   // 0 = bf16 world, 1 = fp32 world
}

// ---------- degree count ----------
__global__ void k_deg(const int* __restrict__ src, const int* __restrict__ dst,
                      unsigned* __restrict__ deg_s, unsigned* __restrict__ deg_d, int E) {
    int i = blockIdx.x * blockDim.x + threadIdx.x;
    if (i < E) {
        atomicAdd(&deg_s[src[i]], 1u);
        atomicAdd(&deg_d[dst[i]], 1u);
    }
}

// ---------- scan stage 1 FUSED with cnorm ----------
__global__ void k_scan1(const unsigned* __restrict__ deg_s, const unsigned* __restrict__ deg_d,
                        float* __restrict__ c_src, float* __restrict__ c_dst,
                        unsigned* __restrict__ bsum, int n) {
    __shared__ unsigned red[256];
    int t = threadIdx.x, i = blockIdx.x * 256 + t;
    unsigned v = 0u;
    if (i < n) {
        unsigned ds = deg_s[i];
        v = deg_d[i];
        c_src[i] = rsqrtf(fmaxf((float)ds, 1.0f));
        c_dst[i] = rsqrtf(fmaxf((float)v, 1.0f));
    }
    red[t] = v;
    __syncthreads();
    for (int o = 128; o > 0; o >>= 1) {
        if (t < o) red[t] += red[t + o];
        __syncthreads();
    }
    if (t == 0) bsum[blockIdx.x] = red[0];
}

// ---------- scan stage 2 ----------
__global__ void k_scan2(const unsigned* __restrict__ bsum, unsigned* __restrict__ bpre, int nb) {
    __shared__ unsigned s[512];
    int t = threadIdx.x;
    unsigned v = (t < nb) ? bsum[t] : 0u;
    s[t] = v;
    __syncthreads();
    for (int o = 1; o < 512; o <<= 1) {
        unsigned x = (t >= o) ? s[t - o] : 0u;
        __syncthreads();
        s[t] += x;
        __syncthreads();
    }
    if (t < nb) bpre[t] = s[t] - v;
}

// ---------- scan stage 3: row_ptr + cursor ----------
__global__ void k_scan3(const unsigned* __restrict__ deg, const unsigned* __restrict__ bpre,
                        unsigned* __restrict__ row_ptr, unsigned* __restrict__ cursor,
                        int n, int E) {
    __shared__ unsigned s[256];
    int t = threadIdx.x, i = blockIdx.x * 256 + t;
    unsigned v = (i < n) ? deg[i] : 0u;
    s[t] = v;
    __syncthreads();
    for (int o = 1; o < 256; o <<= 1) {
        unsigned x = (t >= o) ? s[t - o] : 0u;
        __syncthreads();
        s[t] += x;
        __syncthreads();
    }
    unsigned excl = bpre[blockIdx.x] + s[t] - v;
    if (i < n) { row_ptr[i] = excl; cursor[i] = excl; }
    if (blockIdx.x == 0 && t == 0) row_ptr[n] = (unsigned)E;
}

// ---------- CSR fill FUSED with wsum ----------
__global__ void k_fill(const int* __restrict__ src, const int* __restrict__ dst,
                       unsigned* __restrict__ cursor, unsigned* __restrict__ col,
                       const float* __restrict__ c_dst, float* __restrict__ wsum, int E) {
    int e = blockIdx.x * blockDim.x + threadIdx.x;
    if (e < E) {
        int s = src[e], d = dst[e];
        unsigned p = atomicAdd(&cursor[d], 1u);
        col[p] = (unsigned)s;
        unsafeAtomicAdd(&wsum[s], c_dst[d]);
    }
}

// ---------- layer1 fused: gather (x8 unroll) -> bf16 LDS tile -> MFMA GEMM ----------
// SINGLE CHANGE vs round 13: gather unroll ladder deepened to x8/x4/scalar
// (8 independent 4B loads in flight per lane; probes latency- vs L3-BW-bound).
template <typename T>
__global__ __launch_bounds__(256) void k_layer1(const unsigned* __restrict__ flag, unsigned want,
                                                const T* __restrict__ feat, const T* __restrict__ W1,
                                                const T* __restrict__ b1,
                                                const float* __restrict__ c_src,
                                                const float* __restrict__ c_dst,
                                                const float* __restrict__ wsum,
                                                const unsigned* __restrict__ row_ptr,
                                                const unsigned* __restrict__ col,
                                                float* __restrict__ accum128, int n) {
    if (*flag != want) return;
    __shared__ __align__(16) u16 Wt[64 * 144];    // 18.0 KB; row stride 144 el = 288 B
    __shared__ __align__(16) u16 xsb[64 * 144];   // 18.0 KB
    __shared__ float b1l[FD];
    __shared__ float cdl[64], wcl[64];
    __shared__ float part[4][FD];
    int t = threadIdx.x;
    int base = blockIdx.x * 64;

    if (t < FD) b1l[t] = ldf(b1, t);
    if (t < 64) {
        int rr = base + t;
        cdl[t] = (rr < n) ? c_dst[rr] : 0.0f;
        wcl[t] = (rr < n) ? wsum[rr] * c_src[rr] : 0.0f;
    }
    {   // stage Wt half 0: Wt[nn][k] = W1[k][nn]
        int k = t & 127;
        for (int nn = t >> 7; nn < 64; nn += 2)
            Wt[nn * 144 + k] = f2us(ldf(W1, (size_t)k * FD + nn));
    }
    __syncthreads();

    int w = t >> 6, l = t & 63;
    int m0 = w * 16;                 // wave's local node base
    int q = l >> 4, lm = l & 15;
    int j0 = l * 2;                  // gather: lane owns features 2l, 2l+1

    // ---- gather 16 nodes, x8/x4/scalar unroll ladder, store bf16 pairs to xsb ----
    for (int g = 0; g < 16; g++) {
        int node = base + m0 + g;
        float acc0 = 0.0f, acc1 = 0.0f;
        if (node < n) {
            unsigned qq = row_ptr[node], qe = row_ptr[node + 1];
            for (; qq + 8 <= qe; qq += 8) {       // 8 independent 4B loads in flight
                unsigned s0 = col[qq],     s1 = col[qq + 1], s2 = col[qq + 2], s3 = col[qq + 3];
                unsigned s4 = col[qq + 4], s5 = col[qq + 5], s6 = col[qq + 6], s7 = col[qq + 7];
                float a0, b0, a1, b1v, a2, b2, a3, b3, a4, b4, a5, b5, a6, b6, a7, b7;
                ld2(feat, (size_t)s0 * FD + j0, a0, b0);
                ld2(feat, (size_t)s1 * FD + j0, a1, b1v);
                ld2(feat, (size_t)s2 * FD + j0, a2, b2);
                ld2(feat, (size_t)s3 * FD + j0, a3, b3);
                ld2(feat, (size_t)s4 * FD + j0, a4, b4);
                ld2(feat, (size_t)s5 * FD + j0, a5, b5);
                ld2(feat, (size_t)s6 * FD + j0, a6, b6);
                ld2(feat, (size_t)s7 * FD + j0, a7, b7);
                float c0 = c_src[s0], c1 = c_src[s1], c2 = c_src[s2], c3 = c_src[s3];
                float c4 = c_src[s4], c5 = c_src[s5], c6 = c_src[s6], c7 = c_src[s7];
                acc0 += c0 * a0 + c1 * a1 + c2 * a2 + c3 * a3;
                acc1 += c0 * b0 + c1 * b1v + c2 * b2 + c3 * b3;
                acc0 += c4 * a4 + c5 * a5 + c6 * a6 + c7 * a7;
                acc1 += c4 * b4 + c5 * b5 + c6 * b6 + c7 * b7;
            }
            for (; qq + 4 <= qe; qq += 4) {
                unsigned s0 = col[qq], s1 = col[qq + 1], s2 = col[qq + 2], s3 = col[qq + 3];
                float a0, b0, a1, b1v, a2, b2, a3, b3;
                ld2(feat, (size_t)s0 * FD + j0, a0, b0);
                ld2(feat, (size_t)s1 * FD + j0, a1, b1v);
                ld2(feat, (size_t)s2 * FD + j0, a2, b2);
                ld2(feat, (size_t)s3 * FD + j0, a3, b3);
                float c0 = c_src[s0], c1 = c_src[s1], c2 = c_src[s2], c3 = c_src[s3];
                acc0 += c0 * a0 + c1 * a1 + c2 * a2 + c3 * a3;
                acc1 += c0 * b0 + c1 * b1v + c2 * b2 + c3 * b3;
            }
            for (; qq < qe; qq++) {
                unsigned s = col[qq];
                float a, b;
                ld2(feat, (size_t)s * FD + j0, a, b);
                float c = c_src[s];
                acc0 += c * a;
                acc1 += c * b;
            }
        }
        u32 pk = ((u32)f2us(acc1) << 16) | (u32)f2us(acc0);
        *(u32*)&xsb[(m0 + g) * 144 + j0] = pk;    // wave-private row: no barrier
    }

    // ---- A fragments (reused across all 8 N-tiles) ----
    short8 af[4];
    #pragma unroll
    for (int s = 0; s < 4; s++)
        af[s] = *(const short8*)&xsb[(m0 + lm) * 144 + s * 32 + q * 8];

    float psum[8];
    for (int h = 0; h < 2; h++) {
        if (h == 1) {
            __syncthreads();     // all waves done reading Wt half 0
            int k = t & 127;
            for (int nn = t >> 7; nn < 64; nn += 2)
                Wt[nn * 144 + k] = f2us(ldf(W1, (size_t)k * FD + 64 + nn));
            __syncthreads();
        }
        #pragma unroll
        for (int tt = 0; tt < 4; tt++) {
            f32x4 c = {0.0f, 0.0f, 0.0f, 0.0f};
            #pragma unroll
            for (int s = 0; s < 4; s++) {
                short8 bfr = *(const short8*)&Wt[(tt * 16 + lm) * 144 + s * 32 + q * 8];
                c = __builtin_amdgcn_mfma_f32_16x16x32_bf16(af[s], bfr, c, 0, 0, 0);
            }
            int nglob = h * 64 + tt * 16 + lm;
            float bb = b1l[nglob];
            float ps = 0.0f;
            #pragma unroll
            for (int r = 0; r < 4; r++) {
                int loc = m0 + q * 4 + r;    // block-local node of this C row
                float hv = fmaxf(c[r] * cdl[loc] + bb, 0.0f);
                ps += wcl[loc] * hv;
            }
            psum[h * 4 + tt] = ps;
        }
    }

    // ---- reduce psums across quads (lanes l, l+16, l+32, l+48 share feature) ----
    #pragma unroll
    for (int i = 0; i < 8; i++) {
        float v = psum[i];
        v += __shfl_down(v, 32);
        v += __shfl_down(v, 16);
        if (l < 16) part[w][(i >> 2) * 64 + (i & 3) * 16 + lm] = v;
    }
    __syncthreads();
    if (t < FD) {
        float v = part[0][t] + part[1][t] + part[2][t] + part[3][t];
        unsafeAtomicAdd(&accum128[t], v);
    }
}

// ---------- final tiny GEMM: out = (accum128/N) @ W2 + b2 ----------
template <typename T, typename TO>
__global__ void k_final(const unsigned* __restrict__ flag, unsigned want,
                        const float* __restrict__ accum128,
                        const T* __restrict__ W2, const T* __restrict__ b2v,
                        TO* __restrict__ out, float invN) {
    if (*flag != want) return;
    int j = threadIdx.x;   // 64 threads
    float acc = 0.0f;
    for (int k = 0; k < FD; k++) acc += accum128[k] * ldf(W2, (size_t)k * OD + j);
    float v = acc * invN + ldf(b2v, j);
    if constexpr (sizeof(TO) == 2) out[j] = __float2bfloat16(v);
    else                           out[j] = (TO)v;
}

extern "C" void kernel_launch(void* const* d_in, const int* in_sizes, int n_in,
                              void* d_out, int out_size, void* d_ws, size_t ws_size,
                              hipStream_t stream) {
    const int* src = (const int*)d_in[1];
    const int* dst = (const int*)d_in[2];
    int N = in_sizes[0] / FD;
    int E = in_sizes[1];

    // workspace: zeroed region is one contiguous span [4096, 1048576 + N*4)
    char* ws = (char*)d_ws;
    unsigned* flag     = (unsigned*)(ws);
    float*    accum128 = (float*)   (ws + 4096);      // zeroed
    unsigned* deg_s    = (unsigned*)(ws + 65536);     // zeroed (N*4 <= 400KB)
    unsigned* deg_d    = (unsigned*)(ws + 524288);    // zeroed
    float*    wsum     = (float*)   (ws + 1048576);   // zeroed
    float*    c_src    = (float*)   (ws + 1572864);
    float*    c_dst    = (float*)   (ws + 2097152);
    unsigned* bsum     = (unsigned*)(ws + 2564096);
    unsigned* bpre     = (unsigned*)(ws + 2568192);
    unsigned* row_ptr  = (unsigned*)(ws + 2621440);
    unsigned* cursor   = (unsigned*)(ws + 3145728);
    unsigned* col      = (unsigned*)(ws + 3670016);
    // total footprint: 3670016 + E*4 = ~10.1 MB

    hipMemsetAsync(ws + 4096, 0, (size_t)(1048576 - 4096) + (size_t)N * 4, stream);

    int nb = (N + 255) / 256;   // 391 <= 512

    k_sniff<<<1, 64, 0, stream>>>((const u16*)d_in[3], flag);
    k_deg<<<(E + 255) / 256, 256, 0, stream>>>(src, dst, deg_s, deg_d, E);
    k_scan1<<<nb, 256, 0, stream>>>(deg_s, deg_d, c_src, c_dst, bsum, N);
    k_scan2<<<1, 512, 0, stream>>>(bsum, bpre, nb);
    k_scan3<<<nb, 256, 0, stream>>>(deg_d, bpre, row_ptr, cursor, N, E);
    k_fill<<<(E + 255) / 256, 256, 0, stream>>>(src, dst, cursor, col, c_dst, wsum, E);

    int gl1 = (N + 63) / 64;
    k_layer1<bf16><<<gl1, 256, 0, stream>>>(flag, 0u, (const bf16*)d_in[0], (const bf16*)d_in[3],
                                            (const bf16*)d_in[4], c_src, c_dst, wsum,
                                            row_ptr, col, accum128, N);
    k_layer1<float><<<gl1, 256, 0, stream>>>(flag, 1u, (const float*)d_in[0], (const float*)d_in[3],
                                             (const float*)d_in[4], c_src, c_dst, wsum,
                                             row_ptr, col, accum128, N);

    float invN = 1.0f / (float)N;
    k_final<bf16, bf16><<<1, 64, 0, stream>>>(flag, 0u, accum128, (const bf16*)d_in[5],
                                              (const bf16*)d_in[6], (bf16*)d_out, invN);
    k_final<float, float><<<1, 64, 0, stream>>>(flag, 1u, accum128, (const float*)d_in[5],
                                                (const float*)d_in[6], (float*)d_out, invN);
}